// Round 5
// baseline (22.023 us; speedup 1.0000x reference)
//
#include <hip/hip_runtime.h>
#include <stdint.h>

// ContrastLoss: B=2, M=2048, T=4096, K=16, DT=150
// Band bins of rfft(150) kept: k = 4..20 (17 bins). Mean-subtract & /dt cancel.
// Per-segment Goertzel -> normalized PSD -> closed-form loss from moments.
// ws layout (f32, transposed): ws[e*4096 + r], e=0 -> per-row sum of psd^2,
// e=1..17 -> per-row column sums of normalized psd.

#define T_LEN 4096
#define KSEG 16
#define NROWS 4096      // B*M
#define DTLEN 150
#define NBIN 17
#define SEG_STRIDE 154  // floats; banks (154*s+n)%32 = (26s+n)%32 distinct for s<16

// c_k = 2*cos(2*pi*k/150), k = 4..21 (21 is a dummy pad slot, never used)
__device__ __constant__ float C2TAB[18] = {
  1.9719921f, 1.9562952f, 1.9371663f, 1.9146390f, 1.8887527f, 1.8595530f,
  1.8270909f, 1.7914235f, 1.7526134f, 1.7107286f, 1.6658425f, 1.6180340f,
  1.5673869f, 1.5139901f, 1.4579372f, 1.3993267f, 1.3382612f, 1.2748480f
};

__device__ __forceinline__ void gload_lds(const float* g, float* l) {
  __builtin_amdgcn_global_load_lds(
      (const __attribute__((address_space(1))) void*)g,
      (__attribute__((address_space(3))) void*)l,
      4, 0, 0);
}

// ---------------- Kernel 1: per-row PSD partials (unchanged) ----------------
// 4096 blocks x 64 threads (1 wave per (b,m) row).
// lane: seg = t>>2 (16 segs), g = t&3 (bin groups 5/4/4/4 over 17 bins).
__global__ __launch_bounds__(64) void psd_partials(const float* __restrict__ mo,
                                                   const int* __restrict__ offs,
                                                   float* __restrict__ ws) {
  __shared__ float tile[KSEG * SEG_STRIDE];  // 9856 B

  const int r = blockIdx.x;
  const int t = threadIdx.x;
  const int seg = t >> 2;
  const int g = t & 3;

  const int off = offs[r * KSEG + seg];      // own seg's offset (4-lane broadcast)
  const float* __restrict__ rowp = mo + (size_t)r * T_LEN;

  // stage the 16 segments (150 floats each) into packed LDS, direct-to-LDS
  #pragma unroll
  for (int s = 0; s < KSEG; ++s) {
    const int off_s = __shfl(off, s << 2, 64);
    const float* src = rowp + off_s;
    float* dst = &tile[s * SEG_STRIDE];
    gload_lds(src + t, dst);                       // [0,64)
    gload_lds(src + 64 + t, dst + 64);             // [64,128)
    if (t < DTLEN - 128) gload_lds(src + 128 + t, dst + 128);  // [128,150)
  }
  __syncthreads();

  // bin group: g0 -> bins 4..8 (5), g1 -> 9..12, g2 -> 13..16, g3 -> 17..20
  const int boff = (g == 0) ? 0 : (1 + 4 * g);     // table index of first bin
  float c[5], s1[5], s2[5];
  #pragma unroll
  for (int j = 0; j < 5; ++j) {
    c[j] = C2TAB[boff + j];
    s1[j] = 0.0f;
    s2[j] = 0.0f;
  }

  const float* __restrict__ x = &tile[seg * SEG_STRIDE];
  #pragma unroll 5
  for (int n = 0; n < DTLEN; n += 2) {
    float x0 = x[n];
    float x1 = x[n + 1];
    #pragma unroll
    for (int j = 0; j < 5; ++j) {
      s2[j] = fmaf(c[j], s1[j], x0 - s2[j]);
      s1[j] = fmaf(c[j], s2[j], x1 - s1[j]);
    }
  }

  float p[5];
  #pragma unroll
  for (int j = 0; j < 5; ++j)
    p[j] = fmaf(s1[j], s1[j], s2[j] * s2[j]) - c[j] * s1[j] * s2[j];
  if (g != 0) p[4] = 0.0f;   // 5th slot only real for group 0

  // per-seg band sum across this seg's 4 lanes
  float bs = p[0] + p[1] + p[2] + p[3] + p[4];
  bs += __shfl_xor(bs, 1, 64);
  bs += __shfl_xor(bs, 2, 64);
  const float inv = 1.0f / bs;
  #pragma unroll
  for (int j = 0; j < 5; ++j) p[j] *= inv;

  // total sum of squares (all segs, all bins)
  float ssq = p[0]*p[0] + p[1]*p[1] + p[2]*p[2] + p[3]*p[3] + p[4]*p[4];
  #pragma unroll
  for (int m = 1; m <= 32; m <<= 1) ssq += __shfl_xor(ssq, m, 64);

  // column sums across segs (lanes with equal g, stride 4)
  #pragma unroll
  for (int m = 4; m <= 32; m <<= 1) {
    #pragma unroll
    for (int j = 0; j < 5; ++j) p[j] += __shfl_xor(p[j], m, 64);
  }

  // transposed stores: e=0 plane gets ssq, e=1..17 get column sums
  if (t == 0) ws[r] = ssq;
  if (t < 4) {
    const int nb = (t == 0) ? 5 : 4;
    #pragma unroll
    for (int j = 0; j < 5; ++j)
      if (j < nb) ws[(1 + boff + j) * NROWS + r] = p[j];
  }
}

// ------- Kernel 2: fused column reduction + closed-form scalar (1 block) -------
// 1024 threads = 16 waves. Pair p (0..35): e = p>>1, v = p&1, covers
// ws[e*4096 + v*2048 .. +2048). Wave w handles pairs {w, w+16, w+32}.
__global__ __launch_bounds__(1024) void reduce_final(const float* __restrict__ ws,
                                                     float* __restrict__ out) {
  __shared__ double fin[36];
  const int t = threadIdx.x;
  const int w = t >> 6, lane = t & 63;

  for (int p = w; p < 36; p += 16) {
    const float4* __restrict__ base =
        (const float4*)(ws + (p >> 1) * NROWS + (p & 1) * 2048);
    double a = 0.0;
    #pragma unroll
    for (int q = 0; q < 8; ++q) {
      float4 f = base[lane + 64 * q];
      a += (double)f.x + (double)f.y + (double)f.z + (double)f.w;
    }
    #pragma unroll
    for (int m = 32; m >= 1; m >>= 1) a += __shfl_xor(a, m, 64);
    if (lane == 0) fin[p] = a;
  }
  __syncthreads();

  if (t == 0) {
    double sumA2 = fin[0], sumB2 = fin[1];
    double dAA = 0.0, dBB = 0.0, dAB = 0.0;
    #pragma unroll
    for (int f = 0; f < NBIN; ++f) {
      double ca = fin[2 * (1 + f)];
      double cb = fin[2 * (1 + f) + 1];
      dAA += ca * ca;
      dBB += cb * cb;
      dAB += ca * cb;
    }
    const double N = 32768.0;
    const double invFb   = 1.0 / 17.0;
    const double invNN1  = 1.0 / (32768.0 * 32767.0);
    const double invNN   = 1.0 / (32768.0 * 32768.0);
    double pAA = (2.0 * N * sumA2 - 2.0 * dAA) * invFb;
    double pBB = (2.0 * N * sumB2 - 2.0 * dBB) * invFb;
    double pAB = (N * sumA2 + N * sumB2 - 2.0 * dAB) * invFb;
    double selfa = pAA * invNN1;
    double selfb = pBB * invNN1;
    out[0] = (float)(0.5 * (selfa + selfb) + pAB * invNN);
  }
}

extern "C" void kernel_launch(void* const* d_in, const int* in_sizes, int n_in,
                              void* d_out, int out_size, void* d_ws, size_t ws_size,
                              hipStream_t stream) {
  const float* mo = (const float*)d_in[0];   // (2, 2048, 4096) f32
  const int* offs = (const int*)d_in[1];     // (2, 2048, 16) i32
  float* out = (float*)d_out;
  float* ws = (float*)d_ws;                  // 18*4096*4 = 294912 B used

  psd_partials<<<NROWS, 64, 0, stream>>>(mo, offs, ws);
  reduce_final<<<1, 1024, 0, stream>>>(ws, out);
}

// Round 7
// 21.787 us; speedup vs baseline: 1.0108x; 1.0108x over previous
//
#include <hip/hip_runtime.h>
#include <stdint.h>

// ContrastLoss: B=2, M=2048, T=4096, K=16, DT=150
// Band bins of rfft(150) kept: k = 4..20 (17 bins). Mean-subtract & /dt cancel.
// Per-segment Goertzel -> normalized PSD -> closed-form loss from moments.
// ws layout (f32, transposed): ws[e*4096 + r], e=0 -> per-row sum of psd^2,
// e=1..17 -> per-row column sums of normalized psd.

#define T_LEN 4096
#define KSEG 16
#define NROWS 4096      // B*M
#define DTLEN 150
#define NBIN 17
#define SEG_STRIDE 156  // floats; 16B-aligned (156*4=624=39*16); banks (28s+ph+n)%32 -> <=2-way

typedef float v2f __attribute__((ext_vector_type(2)));

// c_k = 2*cos(2*pi*k/150), k = 4..21 (21 is a dummy pad slot, never used)
__device__ __constant__ float C2TAB[18] = {
  1.9719921f, 1.9562952f, 1.9371663f, 1.9146390f, 1.8887527f, 1.8595530f,
  1.8270909f, 1.7914235f, 1.7526134f, 1.7107286f, 1.6658425f, 1.6180340f,
  1.5673869f, 1.5139901f, 1.4579372f, 1.3993267f, 1.3382612f, 1.2748480f
};

__device__ __forceinline__ void gload_lds16(const float* g, float* l) {
  __builtin_amdgcn_global_load_lds(
      (const __attribute__((address_space(1))) void*)g,
      (__attribute__((address_space(3))) void*)l,
      16, 0, 0);
}

// ---------------- Kernel 1: per-row PSD partials ----------------
// 4096 blocks x 64 threads (1 wave per (b,m) row).
// lane: seg = t>>2 (16 segs), g = t&3 (bin groups 5/4/4/4 over 17 bins).
__global__ __launch_bounds__(64) void psd_partials(const float* __restrict__ mo,
                                                   const int* __restrict__ offs,
                                                   float* __restrict__ ws) {
  __shared__ float tile[KSEG * SEG_STRIDE];  // 9984 B

  const int r = blockIdx.x;
  const int t = threadIdx.x;
  const int seg = t >> 2;
  const int g = t & 3;

  const int off = offs[r * KSEG + seg];      // own seg's offset (4-lane broadcast)
  const float* __restrict__ rowp = mo + (size_t)r * T_LEN;

  // Stage 16 segments: one width-16 global_load_lds per segment.
  // Floor offset to 16B (phase = off&3 handled at read time). Lanes 0..37
  // always needed; lane 38 only when phase==3 (proof: off<=3946 keeps all
  // needed lanes inside the row).
  #pragma unroll
  for (int s = 0; s < KSEG; ++s) {
    const int off_s = __shfl(off, s << 2, 64);
    const int al = off_s & ~3;
    const int bound = 37 + ((off_s & 3) == 3);
    if (t <= bound)
      gload_lds16(rowp + al + 4 * t, &tile[s * SEG_STRIDE]);
  }
  __syncthreads();

  // bin group: g0 -> bins 4..8 (5), g1 -> 9..12, g2 -> 13..16, g3 -> 17..20
  const int boff = (g == 0) ? 0 : (1 + 4 * g);     // table index of first bin
  const v2f c01 = {C2TAB[boff], C2TAB[boff + 1]};
  const v2f c23 = {C2TAB[boff + 2], C2TAB[boff + 3]};
  const float c4 = C2TAB[boff + 4];

  v2f a01 = {0.f, 0.f}, a23 = {0.f, 0.f}, b01 = {0.f, 0.f}, b23 = {0.f, 0.f};
  float a4 = 0.f, b4 = 0.f;   // a = s1, b = s2

  const float* __restrict__ x = &tile[seg * SEG_STRIDE + (off & 3)];
  #pragma unroll 5
  for (int n = 0; n < DTLEN; n += 2) {
    const float x0 = x[n];
    const float x1 = x[n + 1];
    const v2f x0v = {x0, x0};
    const v2f x1v = {x1, x1};
    b01 = __builtin_elementwise_fma(c01, a01, x0v - b01);
    b23 = __builtin_elementwise_fma(c23, a23, x0v - b23);
    b4  = fmaf(c4, a4, x0 - b4);
    a01 = __builtin_elementwise_fma(c01, b01, x1v - a01);
    a23 = __builtin_elementwise_fma(c23, b23, x1v - a23);
    a4  = fmaf(c4, b4, x1 - a4);
  }

  // |X_k|^2 = s1^2 + s2^2 - c*s1*s2   (c = 2cos w)
  const v2f p01 = __builtin_elementwise_fma(a01, a01, b01 * b01) - c01 * (a01 * b01);
  const v2f p23 = __builtin_elementwise_fma(a23, a23, b23 * b23) - c23 * (a23 * b23);
  float p[5];
  p[0] = p01.x; p[1] = p01.y; p[2] = p23.x; p[3] = p23.y;
  p[4] = (g == 0) ? (fmaf(a4, a4, b4 * b4) - c4 * a4 * b4) : 0.0f;

  // per-seg band sum across this seg's 4 lanes
  float bs = p[0] + p[1] + p[2] + p[3] + p[4];
  bs += __shfl_xor(bs, 1, 64);
  bs += __shfl_xor(bs, 2, 64);
  const float inv = 1.0f / bs;
  #pragma unroll
  for (int j = 0; j < 5; ++j) p[j] *= inv;

  // total sum of squares (all segs, all bins)
  float ssq = p[0]*p[0] + p[1]*p[1] + p[2]*p[2] + p[3]*p[3] + p[4]*p[4];
  #pragma unroll
  for (int m = 1; m <= 32; m <<= 1) ssq += __shfl_xor(ssq, m, 64);

  // column sums across segs (lanes with equal g, stride 4)
  #pragma unroll
  for (int m = 4; m <= 32; m <<= 1) {
    #pragma unroll
    for (int j = 0; j < 5; ++j) p[j] += __shfl_xor(p[j], m, 64);
  }

  // transposed stores: e=0 plane gets ssq, e=1..17 get column sums
  if (t == 0) ws[r] = ssq;
  if (t < 4) {
    const int nb = (t == 0) ? 5 : 4;
    #pragma unroll
    for (int j = 0; j < 5; ++j)
      if (j < nb) ws[(1 + boff + j) * NROWS + r] = p[j];
  }
}

// ------- Kernel 2: fused column reduction + closed-form scalar (1 block) -------
// 1024 threads = 16 waves. Pair p (0..35): e = p>>1, v = p&1, covers
// ws[e*4096 + v*2048 .. +2048). Wave w handles pairs {w, w+16, w+32}.
__global__ __launch_bounds__(1024) void reduce_final(const float* __restrict__ ws,
                                                     float* __restrict__ out) {
  __shared__ double fin[36];
  const int t = threadIdx.x;
  const int w = t >> 6, lane = t & 63;

  for (int p = w; p < 36; p += 16) {
    const float4* __restrict__ base =
        (const float4*)(ws + (p >> 1) * NROWS + (p & 1) * 2048);
    double a = 0.0;
    #pragma unroll
    for (int q = 0; q < 8; ++q) {
      float4 f = base[lane + 64 * q];
      a += (double)f.x + (double)f.y + (double)f.z + (double)f.w;
    }
    #pragma unroll
    for (int m = 32; m >= 1; m >>= 1) a += __shfl_xor(a, m, 64);
    if (lane == 0) fin[p] = a;
  }
  __syncthreads();

  if (t == 0) {
    double sumA2 = fin[0], sumB2 = fin[1];
    double dAA = 0.0, dBB = 0.0, dAB = 0.0;
    #pragma unroll
    for (int f = 0; f < NBIN; ++f) {
      double ca = fin[2 * (1 + f)];
      double cb = fin[2 * (1 + f) + 1];
      dAA += ca * ca;
      dBB += cb * cb;
      dAB += ca * cb;
    }
    const double N = 32768.0;
    const double invFb   = 1.0 / 17.0;
    const double invNN1  = 1.0 / (32768.0 * 32767.0);
    const double invNN   = 1.0 / (32768.0 * 32768.0);
    double pAA = (2.0 * N * sumA2 - 2.0 * dAA) * invFb;
    double pBB = (2.0 * N * sumB2 - 2.0 * dBB) * invFb;
    double pAB = (N * sumA2 + N * sumB2 - 2.0 * dAB) * invFb;
    double selfa = pAA * invNN1;
    double selfb = pBB * invNN1;
    out[0] = (float)(0.5 * (selfa + selfb) + pAB * invNN);
  }
}

extern "C" void kernel_launch(void* const* d_in, const int* in_sizes, int n_in,
                              void* d_out, int out_size, void* d_ws, size_t ws_size,
                              hipStream_t stream) {
  const float* mo = (const float*)d_in[0];   // (2, 2048, 4096) f32
  const int* offs = (const int*)d_in[1];     // (2, 2048, 16) i32
  float* out = (float*)d_out;
  float* ws = (float*)d_ws;                  // 18*4096*4 = 294912 B used

  psd_partials<<<NROWS, 64, 0, stream>>>(mo, offs, ws);
  reduce_final<<<1, 1024, 0, stream>>>(ws, out);
}